// Round 13
// baseline (104.036 us; speedup 1.0000x reference)
//
#include <hip/hip_runtime.h>

// Chamfer distance: B=8, N=M=8192, D=3, fp32, via bf16 split-precision MFMA.
// R20: R15-R19: five scheduling nulls (occupancy x2.2, L2 traffic /2, MFMA
//   batching, prefetch depth 3) — per-wave-phase time pinned ~774 cyc vs
//   ~230 issue demand, MfmaUtil ~31% invariant. Stop paying the mystery
//   stall twice: the reference uses ONE distance matrix for both
//   directions (row-mins = pred->gt, col-mins = gt->pred); we computed it
//   twice. One-pass halves total MFMAs/phases chip-wide (1.05M -> 524K).
//   - grid (8 b, 64 n-chunks); block = 128 n (4 n-tiles, all waves);
//     4 waves each stream a disjoint m-QUARTER (64 m-tiles, 32 phases,
//     R19 depth-3 rotation + proven FOLD asm unchanged).
//   - col-mins: per phase, min3-tree over p,r + shfl_xor(32) -> 32 final
//     col-mins per m-tile (exact over block's 128 n) -> coalesced stores
//     to colpart[b][yb][m] (16 MB ws, NO atomics; every slot written once).
//   - row-mins: LDS combine of 4 m-quarter waves (48 KB) -> lane reduce
//     -> one atomicAdd per block.
//   - kernel 3 reduces colpart: min over 64 yb per (b,m), sum, atomicAdd.
//   - ws needs 18.9 MB: guarded by ws_size; R19 path as fallback.

#define B_DIM 8
#define N_DIM 8192
#define MT    (N_DIM / 32)      // 256 m-tiles per b
#define BLOCK 256
#define PPW   4                 // n-tiles per wave (= per block)

typedef short  bf16x8 __attribute__((ext_vector_type(8)));
typedef float  f32x16 __attribute__((ext_vector_type(16)));

__device__ __forceinline__ unsigned short bf16_rne(float f) {
    unsigned int u = __float_as_uint(f);
    u += 0x7fffu + ((u >> 16) & 1u);
    return (unsigned short)(u >> 16);
}
__device__ __forceinline__ float bf16f(unsigned short h) {
    return __uint_as_float(((unsigned int)h) << 16);
}

// ---------------- one-pass path ------------------------------------------
// Pack gt as B-fragments. Layout: 16-byte frags [b][mtile][half][m32].
__global__ __launch_bounds__(256) void prep_gt(
    const float* __restrict__ gt, unsigned short* __restrict__ gtpack,
    float* __restrict__ out)
{
    const int i = blockIdx.x * 256 + threadIdx.x;    // 0 .. B*N-1
    if (i == 0) out[0] = 0.0f;
    const float x = gt[3*i+0], y = gt[3*i+1], z = gt[3*i+2];
    const unsigned short hx = bf16_rne(x), hy = bf16_rne(y), hz = bf16_rne(z);
    const unsigned short lx = bf16_rne(x - bf16f(hx));
    const unsigned short ly = bf16_rne(y - bf16f(hy));
    const unsigned short lz = bf16_rne(z - bf16f(hz));
    const float gn = x*x + y*y + z*z;
    const unsigned short gnh = bf16_rne(gn), gnl = bf16_rne(gn - bf16f(gnh));
    const unsigned short one = 0x3F80;

    const int b  = i >> 13, m = i & (N_DIM - 1);
    const int mt = m >> 5,  c = m & 31;
    unsigned short* p0 = gtpack + ((size_t)(b * MT + mt) * 64 + c) * 8;
    unsigned short* p1 = p0 + 32 * 8;
    bf16x8 h0 = {(short)hx,(short)hy,(short)hz,(short)lx,(short)ly,(short)lz,(short)hx,(short)hy};
    bf16x8 h1 = {(short)hz,(short)one,(short)one,(short)gnh,(short)gnl,0,0,0};
    *(bf16x8*)p0 = h0;
    *(bf16x8*)p1 = h1;
}

__global__ __launch_bounds__(BLOCK, 2) void chamfer_main(
    const float* __restrict__ pred, const bf16x8* __restrict__ gtpack,
    float* __restrict__ colpart, float* __restrict__ out)
{
    __shared__ float cbuf[3 * PPW * 16 * 64];   // 48 KB row-combine buffer
    const int b    = blockIdx.x;            // XCD = b%8 -> per-b L2 locality
    const int yb   = blockIdx.y;
    const int w    = threadIdx.x >> 6, lane = threadIdx.x & 63;
    const int halfk = lane >> 5,  col = lane & 31;

    // A fragments: block's 4 n-tiles (shared by all waves).
    const float* srcb = pred + (size_t)b * N_DIM * 3;
    bf16x8 afrag[PPW];
    #pragma unroll
    for (int p = 0; p < PPW; ++p) {
        const int n = (blockIdx.y * 4 + p) * 32 + col;
        const float x = srcb[3*n+0], y = srcb[3*n+1], z = srcb[3*n+2];
        const float ax = -2.f*x, ay = -2.f*y, az = -2.f*z;
        const unsigned short ahx = bf16_rne(ax), ahy = bf16_rne(ay), ahz = bf16_rne(az);
        const unsigned short alx = bf16_rne(ax - bf16f(ahx));
        const unsigned short aly = bf16_rne(ay - bf16f(ahy));
        const unsigned short alz = bf16_rne(az - bf16f(ahz));
        const float pn = x*x + y*y + z*z;
        const unsigned short pnh = bf16_rne(pn), pnl = bf16_rne(pn - bf16f(pnh));
        const unsigned short one = 0x3F80;
        bf16x8 a0 = {(short)ahx,(short)ahy,(short)ahz,(short)ahx,(short)ahy,(short)ahz,(short)alx,(short)aly};
        bf16x8 a1 = {(short)alz,(short)pnh,(short)pnl,(short)one,(short)one,0,0,0};
        afrag[p] = (halfk == 0) ? a0 : a1;
    }

    float best[PPW][16];
    #pragma unroll
    for (int p = 0; p < PPW; ++p)
        #pragma unroll
        for (int r = 0; r < 16; ++r) best[p][r] = 1e30f;

    // Wave w streams m-quarter w: 64 m-tiles from gtpack.
    const bf16x8* bw = gtpack + (size_t)b * (MT * 64) + (size_t)(w * 64) * 64 + lane;
    // col-partial stream pointer: colpart[(b*64+yb)*8192 + (w*64+2*ph)*32 + m32]
    float* cp = colpart + ((size_t)(b * 64 + yb) * N_DIM) + w * 2048;

    // FOLDC: R19-proven FOLD (asm MFMA pair, s_nop 7/3 in-asm, min3 "+v")
    // + col extraction: min3 over regs per d, shfl32 merge, 2 stores.
#define FOLDC(c0_, c1_) { \
        float cm0 = 1e30f, cm1 = 1e30f; \
        _Pragma("unroll") \
        for (int p = 0; p < PPW; ++p) { \
            f32x16 d0, d1; \
            asm volatile( \
                "v_mfma_f32_32x32x16_bf16 %0, %2, %3, 0\n\t" \
                "v_mfma_f32_32x32x16_bf16 %1, %2, %4, 0\n\t" \
                "s_nop 7\n\t" \
                "s_nop 3" \
                : "=&v"(d0), "=&v"(d1) \
                : "v"(afrag[p]), "v"(c0_), "v"(c1_)); \
            __builtin_amdgcn_sched_barrier(0x34); \
            _Pragma("unroll") \
            for (int r = 0; r < 16; ++r) \
                asm("v_min3_f32 %0, %0, %1, %2" \
                    : "+v"(best[p][r]) : "v"(d0[r]), "v"(d1[r])); \
            _Pragma("unroll") \
            for (int r = 0; r < 16; r += 2) { \
                asm("v_min3_f32 %0, %0, %1, %2" \
                    : "+v"(cm0) : "v"(d0[r]), "v"(d0[r+1])); \
                asm("v_min3_f32 %0, %0, %1, %2" \
                    : "+v"(cm1) : "v"(d1[r]), "v"(d1[r+1])); \
            } \
        } \
        cm0 = fminf(cm0, __shfl_xor(cm0, 32, 64)); \
        cm1 = fminf(cm1, __shfl_xor(cm1, 32, 64)); \
        if (lane < 32) { cp[lane] = cm0; cp[lane + 32] = cm1; } \
        cp += 64; \
    }

    // Depth-3 rotation over 32 phases (R19 pattern, half the phases).
    bf16x8 cA0 = bw[0],   cA1 = bw[64];
    bf16x8 cB0 = bw[128], cB1 = bw[192];
    bf16x8 cC0 = bw[256], cC1 = bw[320];
    bf16x8 cD0 = bw[384], cD1 = bw[448];
    bw += 512;
    for (int t = 0; t < 7; ++t) {
        FOLDC(cA0, cA1);  cA0 = bw[0];   cA1 = bw[64];
        FOLDC(cB0, cB1);  cB0 = bw[128]; cB1 = bw[192];
        FOLDC(cC0, cC1);  cC0 = bw[256]; cC1 = bw[320];
        FOLDC(cD0, cD1);  cD0 = bw[384]; cD1 = bw[448];
        bw += 512;
    }
    FOLDC(cA0, cA1);
    FOLDC(cB0, cB1);
    FOLDC(cC0, cC1);
    FOLDC(cD0, cD1);

    // Row-combine: waves 1..3 export best[], wave 0 min-folds (all waves
    // cover the same 128 n, disjoint m) then lane-reduces.
    if (w > 0) {
        #pragma unroll
        for (int p = 0; p < PPW; ++p)
            #pragma unroll
            for (int r = 0; r < 16; ++r)
                cbuf[((w - 1) * 64 + p * 16 + r) * 64 + lane] = best[p][r];
    }
    __syncthreads();
    if (w == 0) {
        float bsum = 0.f;
        #pragma unroll
        for (int p = 0; p < PPW; ++p) {
            float s = 0.f;
            #pragma unroll
            for (int r = 0; r < 16; ++r) {
                float v = best[p][r];
                v = fminf(v, cbuf[(0 * 64 + p * 16 + r) * 64 + lane]);
                v = fminf(v, cbuf[(1 * 64 + p * 16 + r) * 64 + lane]);
                v = fminf(v, cbuf[(2 * 64 + p * 16 + r) * 64 + lane]);
                v = fminf(v, __shfl_xor(v, 1,  64));
                v = fminf(v, __shfl_xor(v, 2,  64));
                v = fminf(v, __shfl_xor(v, 4,  64));
                v = fminf(v, __shfl_xor(v, 8,  64));
                v = fminf(v, __shfl_xor(v, 16, 64));
                s += v;                       // 16 row-mins of this k-half
            }
            bsum += s + __shfl_xor(s, 32, 64);  // + other k-half's 16 rows
        }
        if (lane == 0) {
            const float scale = 100.0f * 0.5f / ((float)B_DIM * (float)N_DIM);
            atomicAdd(out, bsum * scale);
        }
    }
}

// Reduce col partials: min over 64 y-blocks per (b,m), sum, atomicAdd.
__global__ __launch_bounds__(256) void chamfer_colreduce(
    const float* __restrict__ colpart, float* __restrict__ out)
{
    const int idx = blockIdx.x * 256 + threadIdx.x;  // (b*8192 + m)
    const int b = idx >> 13, m = idx & (N_DIM - 1);
    const float* base = colpart + (size_t)b * 64 * N_DIM + m;
    float v0 = 1e30f, v1 = 1e30f, v2 = 1e30f, v3 = 1e30f;
    #pragma unroll
    for (int y = 0; y < 64; y += 4) {
        v0 = fminf(v0, base[(size_t)(y + 0) * N_DIM]);
        v1 = fminf(v1, base[(size_t)(y + 1) * N_DIM]);
        v2 = fminf(v2, base[(size_t)(y + 2) * N_DIM]);
        v3 = fminf(v3, base[(size_t)(y + 3) * N_DIM]);
    }
    float v = fminf(fminf(v0, v1), fminf(v2, v3));
    // block sum -> one atomicAdd
    v += __shfl_xor(v, 1,  64);
    v += __shfl_xor(v, 2,  64);
    v += __shfl_xor(v, 4,  64);
    v += __shfl_xor(v, 8,  64);
    v += __shfl_xor(v, 16, 64);
    v += __shfl_xor(v, 32, 64);
    __shared__ float ws4[4];
    const int w = threadIdx.x >> 6, lane = threadIdx.x & 63;
    if (lane == 0) ws4[w] = v;
    __syncthreads();
    if (threadIdx.x == 0) {
        const float scale = 100.0f * 0.5f / ((float)B_DIM * (float)N_DIM);
        atomicAdd(out, (ws4[0] + ws4[1] + ws4[2] + ws4[3]) * scale);
    }
}

// ---------------- fallback path (R19, proven 92.8us) ----------------------
__global__ __launch_bounds__(256) void fb_prep(
    const float* __restrict__ pred, const float* __restrict__ gt,
    unsigned short* __restrict__ bpack, float* __restrict__ out)
{
    const int i   = blockIdx.x * 256 + threadIdx.x;
    if (i == 0) out[0] = 0.0f;
    const int dir = i >> 16;
    const int bm  = i & 0xFFFF;
    const float* dst = dir ? pred : gt;
    const float x = dst[3*bm+0], y = dst[3*bm+1], z = dst[3*bm+2];
    const unsigned short hx = bf16_rne(x), hy = bf16_rne(y), hz = bf16_rne(z);
    const unsigned short lx = bf16_rne(x - bf16f(hx));
    const unsigned short ly = bf16_rne(y - bf16f(hy));
    const unsigned short lz = bf16_rne(z - bf16f(hz));
    const float gn = x*x + y*y + z*z;
    const unsigned short gnh = bf16_rne(gn), gnl = bf16_rne(gn - bf16f(gnh));
    const unsigned short one = 0x3F80;
    const int b  = bm >> 13, m = bm & (N_DIM - 1);
    const int mt = m >> 5,   c = m & 31;
    const int dirb = (dir << 3) | b;
    unsigned short* p0 = bpack + ((size_t)(dirb * MT + mt) * 64 + c) * 8;
    unsigned short* p1 = p0 + 32 * 8;
    bf16x8 h0 = {(short)hx,(short)hy,(short)hz,(short)lx,(short)ly,(short)lz,(short)hx,(short)hy};
    bf16x8 h1 = {(short)hz,(short)one,(short)one,(short)gnh,(short)gnl,0,0,0};
    *(bf16x8*)p0 = h0;
    *(bf16x8*)p1 = h1;
}

__global__ __launch_bounds__(BLOCK, 2) void fb_partial(
    const float* __restrict__ pred, const float* __restrict__ gt,
    const bf16x8* __restrict__ bpack, float* __restrict__ out)
{
    __shared__ float cbuf[PPW * 16 * 128];
    __shared__ float wsum[2];
    const int dirb = blockIdx.x;
    const int dir  = dirb >> 3, b = dirb & 7;
    const int w    = threadIdx.x >> 6, lane = threadIdx.x & 63;
    const int halfk = lane >> 5,  col = lane & 31;
    const int nsub = w & 1;
    const int mh   = w >> 1;
    const float* src  = dir ? gt : pred;
    const float* srcb = src + (size_t)b * N_DIM * 3;
    bf16x8 afrag[PPW];
    #pragma unroll
    for (int p = 0; p < PPW; ++p) {
        const int n = (blockIdx.y * 8 + nsub * PPW + p) * 32 + col;
        const float x = srcb[3*n+0], y = srcb[3*n+1], z = srcb[3*n+2];
        const float ax = -2.f*x, ay = -2.f*y, az = -2.f*z;
        const unsigned short ahx = bf16_rne(ax), ahy = bf16_rne(ay), ahz = bf16_rne(az);
        const unsigned short alx = bf16_rne(ax - bf16f(ahx));
        const unsigned short aly = bf16_rne(ay - bf16f(ahy));
        const unsigned short alz = bf16_rne(az - bf16f(ahz));
        const float pn = x*x + y*y + z*z;
        const unsigned short pnh = bf16_rne(pn), pnl = bf16_rne(pn - bf16f(pnh));
        const unsigned short one = 0x3F80;
        bf16x8 a0 = {(short)ahx,(short)ahy,(short)ahz,(short)ahx,(short)ahy,(short)ahz,(short)alx,(short)aly};
        bf16x8 a1 = {(short)alz,(short)pnh,(short)pnl,(short)one,(short)one,0,0,0};
        afrag[p] = (halfk == 0) ? a0 : a1;
    }
    float best[PPW][16];
    #pragma unroll
    for (int p = 0; p < PPW; ++p)
        #pragma unroll
        for (int r = 0; r < 16; ++r) best[p][r] = 1e30f;
    const bf16x8* bw = bpack + (size_t)dirb * (MT * 64) + (size_t)(mh * 128) * 64 + lane;
#define FOLD(c0_, c1_) { \
        _Pragma("unroll") \
        for (int p = 0; p < PPW; ++p) { \
            f32x16 d0, d1; \
            asm volatile( \
                "v_mfma_f32_32x32x16_bf16 %0, %2, %3, 0\n\t" \
                "v_mfma_f32_32x32x16_bf16 %1, %2, %4, 0\n\t" \
                "s_nop 7\n\t" \
                "s_nop 3" \
                : "=&v"(d0), "=&v"(d1) \
                : "v"(afrag[p]), "v"(c0_), "v"(c1_)); \
            __builtin_amdgcn_sched_barrier(0x34); \
            _Pragma("unroll") \
            for (int r = 0; r < 16; ++r) \
                asm("v_min3_f32 %0, %0, %1, %2" \
                    : "+v"(best[p][r]) : "v"(d0[r]), "v"(d1[r])); \
        } \
    }
    bf16x8 cA0 = bw[0],   cA1 = bw[64];
    bf16x8 cB0 = bw[128], cB1 = bw[192];
    bf16x8 cC0 = bw[256], cC1 = bw[320];
    bf16x8 cD0 = bw[384], cD1 = bw[448];
    bw += 512;
    for (int t = 0; t < 15; ++t) {
        FOLD(cA0, cA1);  cA0 = bw[0];   cA1 = bw[64];
        FOLD(cB0, cB1);  cB0 = bw[128]; cB1 = bw[192];
        FOLD(cC0, cC1);  cC0 = bw[256]; cC1 = bw[320];
        FOLD(cD0, cD1);  cD0 = bw[384]; cD1 = bw[448];
        bw += 512;
    }
    FOLD(cA0, cA1);
    FOLD(cB0, cB1);
    FOLD(cC0, cC1);
    FOLD(cD0, cD1);
    if (mh == 1) {
        #pragma unroll
        for (int p = 0; p < PPW; ++p)
            #pragma unroll
            for (int r = 0; r < 16; ++r)
                cbuf[(p * 16 + r) * 128 + nsub * 64 + lane] = best[p][r];
    }
    __syncthreads();
    if (mh == 0) {
        float bsum = 0.f;
        #pragma unroll
        for (int p = 0; p < PPW; ++p) {
            float s = 0.f;
            #pragma unroll
            for (int r = 0; r < 16; ++r) {
                float v = fminf(best[p][r], cbuf[(p * 16 + r) * 128 + nsub * 64 + lane]);
                v = fminf(v, __shfl_xor(v, 1,  64));
                v = fminf(v, __shfl_xor(v, 2,  64));
                v = fminf(v, __shfl_xor(v, 4,  64));
                v = fminf(v, __shfl_xor(v, 8,  64));
                v = fminf(v, __shfl_xor(v, 16, 64));
                s += v;
            }
            bsum += s + __shfl_xor(s, 32, 64);
        }
        if (lane == 0) wsum[nsub] = bsum;
    }
    __syncthreads();
    if (threadIdx.x == 0) {
        const float scale = 100.0f * 0.5f / ((float)B_DIM * (float)N_DIM);
        atomicAdd(out, (wsum[0] + wsum[1]) * scale);
    }
}

extern "C" void kernel_launch(void* const* d_in, const int* in_sizes, int n_in,
                              void* d_out, int out_size, void* d_ws, size_t ws_size,
                              hipStream_t stream) {
    const float* pred = (const float*)d_in[0];
    const float* gt   = (const float*)d_in[1];
    float* out = (float*)d_out;

    const size_t GT_BYTES  = (size_t)2 << 20;                 // 2 MiB gtpack
    const size_t COL_BYTES = (size_t)B_DIM * 64 * N_DIM * 4;  // 16 MiB colpart

    if (ws_size >= GT_BYTES + COL_BYTES) {
        unsigned short* gtpack = (unsigned short*)d_ws;
        float* colpart = (float*)((char*)d_ws + GT_BYTES);
        prep_gt<<<(B_DIM * N_DIM) / 256, 256, 0, stream>>>(gt, gtpack, out);
        dim3 grid(B_DIM, N_DIM / 128);      // 8 x 64 = 512 blocks, 2/CU
        chamfer_main<<<grid, BLOCK, 0, stream>>>(pred, (const bf16x8*)gtpack,
                                                 colpart, out);
        chamfer_colreduce<<<(B_DIM * N_DIM) / 256, 256, 0, stream>>>(colpart, out);
    } else {
        unsigned short* bpack = (unsigned short*)d_ws;        // 4 MiB
        fb_prep<<<(2 * B_DIM * N_DIM) / 256, 256, 0, stream>>>(pred, gt, bpack, out);
        dim3 grid(16, N_DIM / 256);
        fb_partial<<<grid, BLOCK, 0, stream>>>(pred, gt, (const bf16x8*)bpack, out);
    }
}